// Round 7
// baseline (1132.736 us; speedup 1.0000x reference)
//
#include <hip/hip_runtime.h>
#include <math.h>

#define FIN 512
#define FH  64
#define FO  32

#define BSH    9      // 512 nodes per dst-bucket
#define BNODES 512
#define BCAP   10240  // bucket capacity (mean 8192, sigma ~90)

typedef __bf16 bf16_t;
typedef bf16_t bf16x8 __attribute__((ext_vector_type(8)));
typedef bf16_t bf16x4 __attribute__((ext_vector_type(4)));
typedef float  f32x4  __attribute__((ext_vector_type(4)));

__device__ __forceinline__ float bf_lo(unsigned u) {
  return __builtin_bit_cast(float, u << 16);
}
__device__ __forceinline__ float bf_hi(unsigned u) {
  return __builtin_bit_cast(float, u & 0xffff0000u);
}

// fused init: zero deg+bcnt (contiguous), build W1T bf16 [64][512], W2T bf16 [32][64]
__global__ __launch_bounds__(256) void k_init(int* __restrict__ p, int n2,
                                              const float* __restrict__ W1,
                                              bf16_t* __restrict__ w1t,
                                              const float* __restrict__ W2,
                                              bf16_t* __restrict__ w2t) {
  int i = blockIdx.x * 256 + threadIdx.x;
  if (i < n2) p[i] = 0;
  if (i < FIN * FH) {
    int c = i >> 9, k = i & 511;
    w1t[i] = (bf16_t)W1[(size_t)k * FH + c];
  }
  if (i < FH * FO) {
    int c = i >> 6, k = i & 63;
    w2t[i] = (bf16_t)W2[(size_t)k * FO + c];
  }
}

// one edge pass: deg histogram + partition (src,dst) into dst-buckets
__global__ __launch_bounds__(256) void k_part(const int* __restrict__ ei,
                                              int* __restrict__ deg,
                                              int* __restrict__ bcnt,
                                              uint2* __restrict__ part, int E) {
  int e = blockIdx.x * 256 + threadIdx.x;
  if (e >= E) return;
  int s = ei[e];
  int d = ei[E + e];
  atomicAdd(&deg[d], 1);
  int b = d >> BSH;
  int pos = atomicAdd(&bcnt[b], 1);
  if (pos < BCAP) part[(size_t)b * BCAP + pos] = make_uint2((unsigned)s, (unsigned)d);
}

__global__ __launch_bounds__(256) void k_scan_block(const int* __restrict__ deg,
                                                    int* __restrict__ rowoff,
                                                    int* __restrict__ bsum,
                                                    float* __restrict__ dinv, int n) {
  __shared__ int s[256];
  int t = threadIdx.x;
  int i = blockIdx.x * 256 + t;
  int v = (i < n) ? deg[i] : 0;
  s[t] = v;
  __syncthreads();
  #pragma unroll
  for (int off = 1; off < 256; off <<= 1) {
    int tmp = (t >= off) ? s[t - off] : 0;
    __syncthreads();
    s[t] += tmp;
    __syncthreads();
  }
  if (i < n) {
    rowoff[i] = s[t] - v;
    dinv[i] = rsqrtf((float)(v + 1));
  }
  if (t == 255) bsum[blockIdx.x] = s[255];
}

__global__ __launch_bounds__(256) void k_scan_bsum(int* __restrict__ bsum, int nb) {
  __shared__ int s[256];
  int t = threadIdx.x;
  int carry = 0;
  for (int base = 0; base < nb; base += 256) {
    int idx = base + t;
    int v = (idx < nb) ? bsum[idx] : 0;
    s[t] = v;
    __syncthreads();
    #pragma unroll
    for (int off = 1; off < 256; off <<= 1) {
      int tmp = (t >= off) ? s[t - off] : 0;
      __syncthreads();
      s[t] += tmp;
      __syncthreads();
    }
    if (idx < nb) bsum[idx] = s[t] - v + carry;
    carry += s[255];
    __syncthreads();
  }
}

__global__ __launch_bounds__(256) void k_scan_add(int* __restrict__ rowoff,
                                                  const int* __restrict__ bsum, int n) {
  int i = blockIdx.x * 256 + threadIdx.x;
  if (i < n) rowoff[i] += bsum[blockIdx.x];
}

// per-bucket CSR build in LDS, coalesced dump to global
__global__ __launch_bounds__(256) void k_csrb(const uint2* __restrict__ part,
                                              const int* __restrict__ bcnt,
                                              const int* __restrict__ rowoff,
                                              int* __restrict__ csr, int n) {
  __shared__ int lcur[BNODES];
  __shared__ int lcsr[BCAP];
  int b = blockIdx.x;
  int base = b << BSH;
  int t = threadIdx.x;
  for (int i = t; i < BNODES; i += 256) lcur[i] = 0;
  __syncthreads();
  int bo = rowoff[base];
  int cnt = bcnt[b]; if (cnt > BCAP) cnt = BCAP;
  const uint2* pp = part + (size_t)b * BCAP;
  for (int j = t; j < cnt; j += 256) {
    uint2 pk = pp[j];
    int d = (int)pk.y;
    int pos = atomicAdd(&lcur[d - base], 1);
    lcsr[(rowoff[d] - bo) + pos] = (int)pk.x;
  }
  __syncthreads();
  for (int j = t; j < cnt; j += 256) csr[bo + j] = lcsr[j];
}

// GEMM1 via MFMA: P1[n][64] (bf16) = dinv[n] * (x[n] @ W1). x-read-BW bound.
__global__ __launch_bounds__(256) void k_gemm1(const float* __restrict__ x,
                                               const bf16_t* __restrict__ w1t,
                                               const float* __restrict__ dinv,
                                               bf16_t* __restrict__ P1, int n) {
  int t = threadIdx.x;
  int w = t >> 6, l = t & 63;
  int rowBase = blockIdx.x * 64 + w * 16;
  int fr = l & 15, fk = l >> 4;
  int ar = rowBase + fr; if (ar >= n) ar = n - 1;
  const float* xp = x + (size_t)ar * FIN + fk * 8;
  const bf16_t* wb = w1t + (size_t)fr * FIN + fk * 8;

  f32x4 acc0 = {0.f, 0.f, 0.f, 0.f};
  f32x4 acc1 = {0.f, 0.f, 0.f, 0.f};
  f32x4 acc2 = {0.f, 0.f, 0.f, 0.f};
  f32x4 acc3 = {0.f, 0.f, 0.f, 0.f};

  #pragma unroll 4
  for (int kt = 0; kt < FIN; kt += 32) {
    float4 a0 = *(const float4*)(xp + kt);
    float4 a1 = *(const float4*)(xp + kt + 4);
    bf16x8 av;
    av[0] = (bf16_t)a0.x; av[1] = (bf16_t)a0.y; av[2] = (bf16_t)a0.z; av[3] = (bf16_t)a0.w;
    av[4] = (bf16_t)a1.x; av[5] = (bf16_t)a1.y; av[6] = (bf16_t)a1.z; av[7] = (bf16_t)a1.w;
    bf16x8 b0 = *(const bf16x8*)(wb + kt);
    bf16x8 b1 = *(const bf16x8*)(wb + (size_t)16 * FIN + kt);
    bf16x8 b2 = *(const bf16x8*)(wb + (size_t)32 * FIN + kt);
    bf16x8 b3 = *(const bf16x8*)(wb + (size_t)48 * FIN + kt);
    acc0 = __builtin_amdgcn_mfma_f32_16x16x32_bf16(av, b0, acc0, 0, 0, 0);
    acc1 = __builtin_amdgcn_mfma_f32_16x16x32_bf16(av, b1, acc1, 0, 0, 0);
    acc2 = __builtin_amdgcn_mfma_f32_16x16x32_bf16(av, b2, acc2, 0, 0, 0);
    acc3 = __builtin_amdgcn_mfma_f32_16x16x32_bf16(av, b3, acc3, 0, 0, 0);
  }

  #pragma unroll
  for (int rg = 0; rg < 4; rg++) {
    int grow = rowBase + fk * 4 + rg;
    if (grow < n) {
      float dv = dinv[grow];
      bf16_t* prow = P1 + (size_t)grow * FH + fr;
      prow[0]  = (bf16_t)(dv * acc0[rg]);
      prow[16] = (bf16_t)(dv * acc1[rg]);
      prow[32] = (bf16_t)(dv * acc2[rg]);
      prow[48] = (bf16_t)(dv * acc3[rg]);
    }
  }
}

// gather1: wave = 4 independent 16-lane subgroups, one NODE each.
__global__ __launch_bounds__(256) void k_gather1(const bf16_t* __restrict__ P1,
                                                 const int* __restrict__ csr,
                                                 const int* __restrict__ rowoff,
                                                 const int* __restrict__ deg,
                                                 const float* __restrict__ dinv,
                                                 const float* __restrict__ b1,
                                                 bf16_t* __restrict__ h, int n) {
  int l = threadIdx.x & 63;
  int g = l >> 4, dg = l & 15;
  int wv = (blockIdx.x * 256 + threadIdx.x) >> 6;
  int v = wv * 4 + g;
  if (v >= n) return;
  const uint2* P1v = (const uint2*)P1;
  int base = rowoff[v];
  int cnt = deg[v];
  uint2 sv = P1v[(size_t)v * 16 + dg];  // self loop
  float a0 = bf_lo(sv.x), a1 = bf_hi(sv.x), a2 = bf_lo(sv.y), a3 = bf_hi(sv.y);
  float c0 = 0.f, c1 = 0.f, c2 = 0.f, c3 = 0.f;
  int cnt4 = cnt & ~3;
  int j = 0;
  for (; j < cnt4; j += 4) {
    int u0 = csr[base + j];
    int u1 = csr[base + j + 1];
    int u2 = csr[base + j + 2];
    int u3 = csr[base + j + 3];
    uint2 r0 = P1v[(size_t)u0 * 16 + dg];
    uint2 r1 = P1v[(size_t)u1 * 16 + dg];
    uint2 r2 = P1v[(size_t)u2 * 16 + dg];
    uint2 r3 = P1v[(size_t)u3 * 16 + dg];
    a0 += bf_lo(r0.x); a1 += bf_hi(r0.x); a2 += bf_lo(r0.y); a3 += bf_hi(r0.y);
    c0 += bf_lo(r1.x); c1 += bf_hi(r1.x); c2 += bf_lo(r1.y); c3 += bf_hi(r1.y);
    a0 += bf_lo(r2.x); a1 += bf_hi(r2.x); a2 += bf_lo(r2.y); a3 += bf_hi(r2.y);
    c0 += bf_lo(r3.x); c1 += bf_hi(r3.x); c2 += bf_lo(r3.y); c3 += bf_hi(r3.y);
  }
  for (; j < cnt; j++) {
    int u = csr[base + j];
    uint2 r = P1v[(size_t)u * 16 + dg];
    a0 += bf_lo(r.x); a1 += bf_hi(r.x); a2 += bf_lo(r.y); a3 += bf_hi(r.y);
  }
  a0 += c0; a1 += c1; a2 += c2; a3 += c3;
  float dv = dinv[v];
  float4 bb = ((const float4*)b1)[dg];
  bf16x4 hv;
  hv[0] = (bf16_t)fmaxf(dv * a0 + bb.x, 0.f);
  hv[1] = (bf16_t)fmaxf(dv * a1 + bb.y, 0.f);
  hv[2] = (bf16_t)fmaxf(dv * a2 + bb.z, 0.f);
  hv[3] = (bf16_t)fmaxf(dv * a3 + bb.w, 0.f);
  ((bf16x4*)h)[(size_t)v * 16 + dg] = hv;
}

// GEMM2 via MFMA: P2[n][32] (bf16) = dinv[n] * (h[n] @ W2)
__global__ __launch_bounds__(256) void k_gemm2(const bf16_t* __restrict__ h,
                                               const bf16_t* __restrict__ w2t,
                                               const float* __restrict__ dinv,
                                               bf16_t* __restrict__ P2, int n) {
  int t = threadIdx.x;
  int w = t >> 6, l = t & 63;
  int rowBase = blockIdx.x * 64 + w * 16;
  int fr = l & 15, fk = l >> 4;
  int ar = rowBase + fr; if (ar >= n) ar = n - 1;
  const bf16_t* hp = h + (size_t)ar * FH + fk * 8;
  const bf16_t* wb0 = w2t + (size_t)fr * FH + fk * 8;
  const bf16_t* wb1 = w2t + (size_t)(fr + 16) * FH + fk * 8;

  f32x4 acc0 = {0.f, 0.f, 0.f, 0.f};
  f32x4 acc1 = {0.f, 0.f, 0.f, 0.f};
  #pragma unroll
  for (int kt = 0; kt < FH; kt += 32) {
    bf16x8 af = *(const bf16x8*)(hp + kt);
    bf16x8 b0 = *(const bf16x8*)(wb0 + kt);
    bf16x8 b1 = *(const bf16x8*)(wb1 + kt);
    acc0 = __builtin_amdgcn_mfma_f32_16x16x32_bf16(af, b0, acc0, 0, 0, 0);
    acc1 = __builtin_amdgcn_mfma_f32_16x16x32_bf16(af, b1, acc1, 0, 0, 0);
  }
  #pragma unroll
  for (int rg = 0; rg < 4; rg++) {
    int grow = rowBase + fk * 4 + rg;
    if (grow < n) {
      float dv = dinv[grow];
      P2[(size_t)grow * FO + fr]      = (bf16_t)(dv * acc0[rg]);
      P2[(size_t)grow * FO + fr + 16] = (bf16_t)(dv * acc1[rg]);
    }
  }
}

// gather2 + bias + log_softmax: wave = 8 subgroups x 8 lanes, one node each.
__global__ __launch_bounds__(256) void k_g2final(const bf16_t* __restrict__ P2,
                                                 const int* __restrict__ csr,
                                                 const int* __restrict__ rowoff,
                                                 const int* __restrict__ deg,
                                                 const float* __restrict__ dinv,
                                                 const float* __restrict__ b2,
                                                 float* __restrict__ out, int n) {
  int l = threadIdx.x & 63;
  int g = l >> 3, dg = l & 7;
  int wv = (blockIdx.x * 256 + threadIdx.x) >> 6;
  int v = wv * 8 + g;
  if (v >= n) return;
  const uint2* P2v = (const uint2*)P2;
  int base = rowoff[v];
  int cnt = deg[v];
  uint2 sv = P2v[(size_t)v * 8 + dg];  // self loop
  float a0 = bf_lo(sv.x), a1 = bf_hi(sv.x), a2 = bf_lo(sv.y), a3 = bf_hi(sv.y);
  float c0 = 0.f, c1 = 0.f, c2 = 0.f, c3 = 0.f;
  int cnt4 = cnt & ~3;
  int j = 0;
  for (; j < cnt4; j += 4) {
    int u0 = csr[base + j];
    int u1 = csr[base + j + 1];
    int u2 = csr[base + j + 2];
    int u3 = csr[base + j + 3];
    uint2 r0 = P2v[(size_t)u0 * 8 + dg];
    uint2 r1 = P2v[(size_t)u1 * 8 + dg];
    uint2 r2 = P2v[(size_t)u2 * 8 + dg];
    uint2 r3 = P2v[(size_t)u3 * 8 + dg];
    a0 += bf_lo(r0.x); a1 += bf_hi(r0.x); a2 += bf_lo(r0.y); a3 += bf_hi(r0.y);
    c0 += bf_lo(r1.x); c1 += bf_hi(r1.x); c2 += bf_lo(r1.y); c3 += bf_hi(r1.y);
    a0 += bf_lo(r2.x); a1 += bf_hi(r2.x); a2 += bf_lo(r2.y); a3 += bf_hi(r2.y);
    c0 += bf_lo(r3.x); c1 += bf_hi(r3.x); c2 += bf_lo(r3.y); c3 += bf_hi(r3.y);
  }
  for (; j < cnt; j++) {
    int u = csr[base + j];
    uint2 r = P2v[(size_t)u * 8 + dg];
    a0 += bf_lo(r.x); a1 += bf_hi(r.x); a2 += bf_lo(r.y); a3 += bf_hi(r.y);
  }
  a0 += c0; a1 += c1; a2 += c2; a3 += c3;
  float dv = dinv[v];
  float4 bb = ((const float4*)b2)[dg & 7];
  float v0 = dv * a0 + bb.x;
  float v1 = dv * a1 + bb.y;
  float v2 = dv * a2 + bb.z;
  float v3 = dv * a3 + bb.w;
  float m = fmaxf(fmaxf(v0, v1), fmaxf(v2, v3));
  m = fmaxf(m, __shfl_xor(m, 1, 64));
  m = fmaxf(m, __shfl_xor(m, 2, 64));
  m = fmaxf(m, __shfl_xor(m, 4, 64));
  float se = expf(v0 - m) + expf(v1 - m) + expf(v2 - m) + expf(v3 - m);
  se += __shfl_xor(se, 1, 64);
  se += __shfl_xor(se, 2, 64);
  se += __shfl_xor(se, 4, 64);
  float lse = m + logf(se);
  float4 o;
  o.x = v0 - lse; o.y = v1 - lse; o.z = v2 - lse; o.w = v3 - lse;
  *(float4*)(out + (size_t)v * FO + dg * 4) = o;
}

extern "C" void kernel_launch(void* const* d_in, const int* in_sizes, int n_in,
                              void* d_out, int out_size, void* d_ws, size_t ws_size,
                              hipStream_t stream) {
  const float* x  = (const float*)d_in[0];
  const int*   ei = (const int*)d_in[1];
  const float* W1 = (const float*)d_in[2];
  const float* b1 = (const float*)d_in[3];
  const float* W2 = (const float*)d_in[4];
  const float* b2 = (const float*)d_in[5];
  const int N = in_sizes[0] / FIN;
  const int E = in_sizes[1] / 2;
  float* out = (float*)d_out;

  size_t NP = ((size_t)N + 63) & ~(size_t)63;
  size_t EP = ((size_t)E + 63) & ~(size_t)63;
  int nb = (N + 255) / 256;
  int nbk = (N + BNODES - 1) >> BSH;

  int*    deg    = (int*)d_ws;              // NP
  int*    bcnt   = deg + NP;                // 512 (contiguous with deg for zeroing)
  int*    rowoff = bcnt + 512;              // NP
  int*    bsum   = rowoff + NP;             // 512
  float*  dinv   = (float*)(bsum + 512);    // NP
  int*    csr    = (int*)(dinv + NP);       // EP
  uint2*  part   = (uint2*)(csr + EP);      // nbk*BCAP (16 MB)
  bf16_t* w1t    = (bf16_t*)(part + (size_t)nbk * BCAP);  // 64*512
  bf16_t* w2t    = w1t + (size_t)FH * FIN;  // 32*64
  bf16_t* P1     = w2t + (size_t)FO * FH;   // NP*64
  bf16_t* h      = P1 + NP * FH;            // NP*64
  bf16_t* P2     = h + NP * FH;             // NP*32

  int initN = (int)(NP + 512);
  if (initN < FIN * FH) initN = FIN * FH;
  k_init<<<(initN + 255) / 256, 256, 0, stream>>>(deg, (int)(NP + 512), W1, w1t, W2, w2t);
  k_part<<<(E + 255) / 256, 256, 0, stream>>>(ei, deg, bcnt, part, E);
  k_scan_block<<<nb, 256, 0, stream>>>(deg, rowoff, bsum, dinv, N);
  k_scan_bsum<<<1, 256, 0, stream>>>(bsum, nb);
  k_scan_add<<<nb, 256, 0, stream>>>(rowoff, bsum, N);
  k_csrb<<<nbk, 256, 0, stream>>>(part, bcnt, rowoff, csr, N);
  k_gemm1<<<(N + 63) / 64, 256, 0, stream>>>(x, w1t, dinv, P1, N);
  {
    int waves = (N + 3) / 4;
    k_gather1<<<(waves + 3) / 4, 256, 0, stream>>>(P1, csr, rowoff, deg, dinv, b1, h, N);
  }
  k_gemm2<<<(N + 63) / 64, 256, 0, stream>>>(h, w2t, dinv, P2, N);
  {
    int waves = (N + 7) / 8;
    k_g2final<<<(waves + 3) / 4, 256, 0, stream>>>(P2, csr, rowoff, deg, dinv, b2, out, N);
  }
}

// Round 8
// 264.300 us; speedup vs baseline: 4.2858x; 4.2858x over previous
//
#include <hip/hip_runtime.h>
#include <math.h>

#define FIN 512
#define FH  64
#define FO  32

#define BSH    9          // 512 nodes per dst-bucket
#define BNODES 512
#define NCHUNK 256        // radix chunk-blocks
#define BCAP   16384      // LDS csr capacity per bucket (mean 8192, max ~8600)
#define NBMAX  512        // max buckets supported (N <= 256K)

typedef __bf16 bf16_t;
typedef bf16_t bf16x8 __attribute__((ext_vector_type(8)));
typedef bf16_t bf16x4 __attribute__((ext_vector_type(4)));
typedef float  f32x4  __attribute__((ext_vector_type(4)));

__device__ __forceinline__ float bf_lo(unsigned u) {
  return __builtin_bit_cast(float, u << 16);
}
__device__ __forceinline__ float bf_hi(unsigned u) {
  return __builtin_bit_cast(float, u & 0xffff0000u);
}

// fused init: zero deg, build W1T bf16 [64][512], W2T bf16 [32][64]
__global__ __launch_bounds__(256) void k_init(int* __restrict__ p, int n2,
                                              const float* __restrict__ W1,
                                              bf16_t* __restrict__ w1t,
                                              const float* __restrict__ W2,
                                              bf16_t* __restrict__ w2t) {
  int i = blockIdx.x * 256 + threadIdx.x;
  if (i < n2) p[i] = 0;
  if (i < FIN * FH) {
    int c = i >> 9, k = i & 511;
    w1t[i] = (bf16_t)W1[(size_t)k * FH + c];
  }
  if (i < FH * FO) {
    int c = i >> 6, k = i & 63;
    w2t[i] = (bf16_t)W2[(size_t)k * FO + c];
  }
}

// radix pass A: per-chunk bucket histogram (LDS) + global deg histogram
__global__ __launch_bounds__(256) void k_histA(const int* __restrict__ dst,
                                               int* __restrict__ deg,
                                               int* __restrict__ histmat,
                                               int E, int NB) {
  __shared__ int lh[NBMAX];
  int t = threadIdx.x;
  int g = blockIdx.x;
  for (int i = t; i < NB; i += 256) lh[i] = 0;
  __syncthreads();
  int C = (E + NCHUNK - 1) / NCHUNK;
  int e0 = g * C, e1 = min(E, e0 + C);
  for (int e = e0 + t; e < e1; e += 256) {
    int d = dst[e];
    atomicAdd(&deg[d], 1);
    atomicAdd(&lh[d >> BSH], 1);
  }
  __syncthreads();
  for (int b = t; b < NB; b += 256) histmat[(size_t)b * NCHUNK + g] = lh[b];
}

__global__ __launch_bounds__(256) void k_scan_block(const int* __restrict__ deg,
                                                    int* __restrict__ rowoff,
                                                    int* __restrict__ bsum,
                                                    float* __restrict__ dinv, int n) {
  __shared__ int s[256];
  int t = threadIdx.x;
  int i = blockIdx.x * 256 + t;
  int v = (i < n) ? deg[i] : 0;
  s[t] = v;
  __syncthreads();
  #pragma unroll
  for (int off = 1; off < 256; off <<= 1) {
    int tmp = (t >= off) ? s[t - off] : 0;
    __syncthreads();
    s[t] += tmp;
    __syncthreads();
  }
  if (i < n) {
    rowoff[i] = s[t] - v;
    dinv[i] = rsqrtf((float)(v + 1));
  }
  if (t == 255) bsum[blockIdx.x] = s[255];
}

__global__ __launch_bounds__(256) void k_scan_bsum(int* __restrict__ bsum, int nb) {
  __shared__ int s[256];
  int t = threadIdx.x;
  int carry = 0;
  for (int base = 0; base < nb; base += 256) {
    int idx = base + t;
    int v = (idx < nb) ? bsum[idx] : 0;
    s[t] = v;
    __syncthreads();
    #pragma unroll
    for (int off = 1; off < 256; off <<= 1) {
      int tmp = (t >= off) ? s[t - off] : 0;
      __syncthreads();
      s[t] += tmp;
      __syncthreads();
    }
    if (idx < nb) bsum[idx] = s[t] - v + carry;
    carry += s[255];
    __syncthreads();
  }
}

__global__ __launch_bounds__(256) void k_scan_add(int* __restrict__ rowoff,
                                                  const int* __restrict__ bsum, int n) {
  int i = blockIdx.x * 256 + threadIdx.x;
  if (i < n) rowoff[i] += bsum[blockIdx.x];
}

// radix pass B: block b = exclusive scan of histmat row over chunks, + rowoff[b<<9]
__global__ __launch_bounds__(256) void k_scanB(const int* __restrict__ histmat,
                                               const int* __restrict__ rowoff,
                                               int* __restrict__ offmat, int NB) {
  __shared__ int s[NCHUNK];
  int b = blockIdx.x;
  int t = threadIdx.x;   // == chunk id (NCHUNK == 256)
  int v = histmat[(size_t)b * NCHUNK + t];
  s[t] = v;
  __syncthreads();
  #pragma unroll
  for (int off = 1; off < NCHUNK; off <<= 1) {
    int tmp = (t >= off) ? s[t - off] : 0;
    __syncthreads();
    s[t] += tmp;
    __syncthreads();
  }
  offmat[(size_t)b * NCHUNK + t] = s[t] - v + rowoff[(size_t)b << BSH];
}

// radix pass C: scatter packed (dlocal<<23 | src) into bucket-grouped part[]
__global__ __launch_bounds__(256) void k_scatC(const int* __restrict__ ei,
                                               const int* __restrict__ offmat,
                                               unsigned* __restrict__ part,
                                               int E, int NB) {
  __shared__ int lcur[NBMAX];
  int t = threadIdx.x;
  int g = blockIdx.x;
  for (int b = t; b < NB; b += 256) lcur[b] = offmat[(size_t)b * NCHUNK + g];
  __syncthreads();
  int C = (E + NCHUNK - 1) / NCHUNK;
  int e0 = g * C, e1 = min(E, e0 + C);
  for (int e = e0 + t; e < e1; e += 256) {
    int s = ei[e];
    int d = ei[E + e];
    int b = d >> BSH;
    int pos = atomicAdd(&lcur[b], 1);
    part[pos] = (unsigned)s | ((unsigned)(d & (BNODES - 1)) << 23);
  }
}

// per-bucket CSR build in LDS, coalesced dump
__global__ __launch_bounds__(256) void k_csrb(const unsigned* __restrict__ part,
                                              const int* __restrict__ rowoff,
                                              int* __restrict__ csr, int n, int E) {
  __shared__ int lro[BNODES];   // rowoff[base+dl] - bo
  __shared__ int lcur[BNODES];
  __shared__ int lcsr[BCAP];
  int b = blockIdx.x;
  int base = b << BSH;
  int t = threadIdx.x;
  int bo = rowoff[base];
  int endIdx = base + BNODES;
  int bend = (endIdx < n) ? rowoff[endIdx] : E;
  int cnt = bend - bo;
  for (int i = t; i < BNODES; i += 256) {
    int node = base + i;
    lro[i] = (node < n) ? (rowoff[node] - bo) : cnt;
    lcur[i] = 0;
  }
  __syncthreads();
  const unsigned* pp = part + bo;
  if (cnt <= BCAP) {
    for (int j = t; j < cnt; j += 256) {
      unsigned pk = pp[j];
      int dl = (int)(pk >> 23);
      int pos = atomicAdd(&lcur[dl], 1);
      lcsr[lro[dl] + pos] = (int)(pk & 0x7FFFFFu);
    }
    __syncthreads();
    for (int j = t; j < cnt; j += 256) csr[bo + j] = lcsr[j];
  } else {  // fallback: direct scatter (correct, slower)
    for (int j = t; j < cnt; j += 256) {
      unsigned pk = pp[j];
      int dl = (int)(pk >> 23);
      int pos = atomicAdd(&lcur[dl], 1);
      csr[bo + lro[dl] + pos] = (int)(pk & 0x7FFFFFu);
    }
  }
}

// GEMM1 via MFMA: P1[n][64] (bf16) = dinv[n] * (x[n] @ W1). x-read-BW bound.
__global__ __launch_bounds__(256) void k_gemm1(const float* __restrict__ x,
                                               const bf16_t* __restrict__ w1t,
                                               const float* __restrict__ dinv,
                                               bf16_t* __restrict__ P1, int n) {
  int t = threadIdx.x;
  int w = t >> 6, l = t & 63;
  int rowBase = blockIdx.x * 64 + w * 16;
  int fr = l & 15, fk = l >> 4;
  int ar = rowBase + fr; if (ar >= n) ar = n - 1;
  const float* xp = x + (size_t)ar * FIN + fk * 8;
  const bf16_t* wb = w1t + (size_t)fr * FIN + fk * 8;

  f32x4 acc0 = {0.f, 0.f, 0.f, 0.f};
  f32x4 acc1 = {0.f, 0.f, 0.f, 0.f};
  f32x4 acc2 = {0.f, 0.f, 0.f, 0.f};
  f32x4 acc3 = {0.f, 0.f, 0.f, 0.f};

  #pragma unroll 4
  for (int kt = 0; kt < FIN; kt += 32) {
    float4 a0 = *(const float4*)(xp + kt);
    float4 a1 = *(const float4*)(xp + kt + 4);
    bf16x8 av;
    av[0] = (bf16_t)a0.x; av[1] = (bf16_t)a0.y; av[2] = (bf16_t)a0.z; av[3] = (bf16_t)a0.w;
    av[4] = (bf16_t)a1.x; av[5] = (bf16_t)a1.y; av[6] = (bf16_t)a1.z; av[7] = (bf16_t)a1.w;
    bf16x8 b0 = *(const bf16x8*)(wb + kt);
    bf16x8 b1 = *(const bf16x8*)(wb + (size_t)16 * FIN + kt);
    bf16x8 b2 = *(const bf16x8*)(wb + (size_t)32 * FIN + kt);
    bf16x8 b3 = *(const bf16x8*)(wb + (size_t)48 * FIN + kt);
    acc0 = __builtin_amdgcn_mfma_f32_16x16x32_bf16(av, b0, acc0, 0, 0, 0);
    acc1 = __builtin_amdgcn_mfma_f32_16x16x32_bf16(av, b1, acc1, 0, 0, 0);
    acc2 = __builtin_amdgcn_mfma_f32_16x16x32_bf16(av, b2, acc2, 0, 0, 0);
    acc3 = __builtin_amdgcn_mfma_f32_16x16x32_bf16(av, b3, acc3, 0, 0, 0);
  }

  #pragma unroll
  for (int rg = 0; rg < 4; rg++) {
    int grow = rowBase + fk * 4 + rg;
    if (grow < n) {
      float dv = dinv[grow];
      bf16_t* prow = P1 + (size_t)grow * FH + fr;
      prow[0]  = (bf16_t)(dv * acc0[rg]);
      prow[16] = (bf16_t)(dv * acc1[rg]);
      prow[32] = (bf16_t)(dv * acc2[rg]);
      prow[48] = (bf16_t)(dv * acc3[rg]);
    }
  }
}

// gather1: wave = 4 independent 16-lane subgroups, one NODE each.
__global__ __launch_bounds__(256) void k_gather1(const bf16_t* __restrict__ P1,
                                                 const int* __restrict__ csr,
                                                 const int* __restrict__ rowoff,
                                                 const int* __restrict__ deg,
                                                 const float* __restrict__ dinv,
                                                 const float* __restrict__ b1,
                                                 bf16_t* __restrict__ h, int n) {
  int l = threadIdx.x & 63;
  int g = l >> 4, dg = l & 15;
  int wv = (blockIdx.x * 256 + threadIdx.x) >> 6;
  int v = wv * 4 + g;
  if (v >= n) return;
  const uint2* P1v = (const uint2*)P1;
  int base = rowoff[v];
  int cnt = deg[v];
  uint2 sv = P1v[(size_t)v * 16 + dg];  // self loop
  float a0 = bf_lo(sv.x), a1 = bf_hi(sv.x), a2 = bf_lo(sv.y), a3 = bf_hi(sv.y);
  float c0 = 0.f, c1 = 0.f, c2 = 0.f, c3 = 0.f;
  int cnt4 = cnt & ~3;
  int j = 0;
  for (; j < cnt4; j += 4) {
    int u0 = csr[base + j];
    int u1 = csr[base + j + 1];
    int u2 = csr[base + j + 2];
    int u3 = csr[base + j + 3];
    uint2 r0 = P1v[(size_t)u0 * 16 + dg];
    uint2 r1 = P1v[(size_t)u1 * 16 + dg];
    uint2 r2 = P1v[(size_t)u2 * 16 + dg];
    uint2 r3 = P1v[(size_t)u3 * 16 + dg];
    a0 += bf_lo(r0.x); a1 += bf_hi(r0.x); a2 += bf_lo(r0.y); a3 += bf_hi(r0.y);
    c0 += bf_lo(r1.x); c1 += bf_hi(r1.x); c2 += bf_lo(r1.y); c3 += bf_hi(r1.y);
    a0 += bf_lo(r2.x); a1 += bf_hi(r2.x); a2 += bf_lo(r2.y); a3 += bf_hi(r2.y);
    c0 += bf_lo(r3.x); c1 += bf_hi(r3.x); c2 += bf_lo(r3.y); c3 += bf_hi(r3.y);
  }
  for (; j < cnt; j++) {
    int u = csr[base + j];
    uint2 r = P1v[(size_t)u * 16 + dg];
    a0 += bf_lo(r.x); a1 += bf_hi(r.x); a2 += bf_lo(r.y); a3 += bf_hi(r.y);
  }
  a0 += c0; a1 += c1; a2 += c2; a3 += c3;
  float dv = dinv[v];
  float4 bb = ((const float4*)b1)[dg];
  bf16x4 hv;
  hv[0] = (bf16_t)fmaxf(dv * a0 + bb.x, 0.f);
  hv[1] = (bf16_t)fmaxf(dv * a1 + bb.y, 0.f);
  hv[2] = (bf16_t)fmaxf(dv * a2 + bb.z, 0.f);
  hv[3] = (bf16_t)fmaxf(dv * a3 + bb.w, 0.f);
  ((bf16x4*)h)[(size_t)v * 16 + dg] = hv;
}

// GEMM2 via MFMA: P2[n][32] (bf16) = dinv[n] * (h[n] @ W2)
__global__ __launch_bounds__(256) void k_gemm2(const bf16_t* __restrict__ h,
                                               const bf16_t* __restrict__ w2t,
                                               const float* __restrict__ dinv,
                                               bf16_t* __restrict__ P2, int n) {
  int t = threadIdx.x;
  int w = t >> 6, l = t & 63;
  int rowBase = blockIdx.x * 64 + w * 16;
  int fr = l & 15, fk = l >> 4;
  int ar = rowBase + fr; if (ar >= n) ar = n - 1;
  const bf16_t* hp = h + (size_t)ar * FH + fk * 8;
  const bf16_t* wb0 = w2t + (size_t)fr * FH + fk * 8;
  const bf16_t* wb1 = w2t + (size_t)(fr + 16) * FH + fk * 8;

  f32x4 acc0 = {0.f, 0.f, 0.f, 0.f};
  f32x4 acc1 = {0.f, 0.f, 0.f, 0.f};
  #pragma unroll
  for (int kt = 0; kt < FH; kt += 32) {
    bf16x8 af = *(const bf16x8*)(hp + kt);
    bf16x8 b0 = *(const bf16x8*)(wb0 + kt);
    bf16x8 b1 = *(const bf16x8*)(wb1 + kt);
    acc0 = __builtin_amdgcn_mfma_f32_16x16x32_bf16(af, b0, acc0, 0, 0, 0);
    acc1 = __builtin_amdgcn_mfma_f32_16x16x32_bf16(af, b1, acc1, 0, 0, 0);
  }
  #pragma unroll
  for (int rg = 0; rg < 4; rg++) {
    int grow = rowBase + fk * 4 + rg;
    if (grow < n) {
      float dv = dinv[grow];
      P2[(size_t)grow * FO + fr]      = (bf16_t)(dv * acc0[rg]);
      P2[(size_t)grow * FO + fr + 16] = (bf16_t)(dv * acc1[rg]);
    }
  }
}

// gather2 + bias + log_softmax: wave = 8 subgroups x 8 lanes, one node each.
__global__ __launch_bounds__(256) void k_g2final(const bf16_t* __restrict__ P2,
                                                 const int* __restrict__ csr,
                                                 const int* __restrict__ rowoff,
                                                 const int* __restrict__ deg,
                                                 const float* __restrict__ dinv,
                                                 const float* __restrict__ b2,
                                                 float* __restrict__ out, int n) {
  int l = threadIdx.x & 63;
  int g = l >> 3, dg = l & 7;
  int wv = (blockIdx.x * 256 + threadIdx.x) >> 6;
  int v = wv * 8 + g;
  if (v >= n) return;
  const uint2* P2v = (const uint2*)P2;
  int base = rowoff[v];
  int cnt = deg[v];
  uint2 sv = P2v[(size_t)v * 8 + dg];  // self loop
  float a0 = bf_lo(sv.x), a1 = bf_hi(sv.x), a2 = bf_lo(sv.y), a3 = bf_hi(sv.y);
  float c0 = 0.f, c1 = 0.f, c2 = 0.f, c3 = 0.f;
  int cnt4 = cnt & ~3;
  int j = 0;
  for (; j < cnt4; j += 4) {
    int u0 = csr[base + j];
    int u1 = csr[base + j + 1];
    int u2 = csr[base + j + 2];
    int u3 = csr[base + j + 3];
    uint2 r0 = P2v[(size_t)u0 * 8 + dg];
    uint2 r1 = P2v[(size_t)u1 * 8 + dg];
    uint2 r2 = P2v[(size_t)u2 * 8 + dg];
    uint2 r3 = P2v[(size_t)u3 * 8 + dg];
    a0 += bf_lo(r0.x); a1 += bf_hi(r0.x); a2 += bf_lo(r0.y); a3 += bf_hi(r0.y);
    c0 += bf_lo(r1.x); c1 += bf_hi(r1.x); c2 += bf_lo(r1.y); c3 += bf_hi(r1.y);
    a0 += bf_lo(r2.x); a1 += bf_hi(r2.x); a2 += bf_lo(r2.y); a3 += bf_hi(r2.y);
    c0 += bf_lo(r3.x); c1 += bf_hi(r3.x); c2 += bf_lo(r3.y); c3 += bf_hi(r3.y);
  }
  for (; j < cnt; j++) {
    int u = csr[base + j];
    uint2 r = P2v[(size_t)u * 8 + dg];
    a0 += bf_lo(r.x); a1 += bf_hi(r.x); a2 += bf_lo(r.y); a3 += bf_hi(r.y);
  }
  a0 += c0; a1 += c1; a2 += c2; a3 += c3;
  float dv = dinv[v];
  float4 bb = ((const float4*)b2)[dg & 7];
  float v0 = dv * a0 + bb.x;
  float v1 = dv * a1 + bb.y;
  float v2 = dv * a2 + bb.z;
  float v3 = dv * a3 + bb.w;
  float m = fmaxf(fmaxf(v0, v1), fmaxf(v2, v3));
  m = fmaxf(m, __shfl_xor(m, 1, 64));
  m = fmaxf(m, __shfl_xor(m, 2, 64));
  m = fmaxf(m, __shfl_xor(m, 4, 64));
  float se = expf(v0 - m) + expf(v1 - m) + expf(v2 - m) + expf(v3 - m);
  se += __shfl_xor(se, 1, 64);
  se += __shfl_xor(se, 2, 64);
  se += __shfl_xor(se, 4, 64);
  float lse = m + logf(se);
  float4 o;
  o.x = v0 - lse; o.y = v1 - lse; o.z = v2 - lse; o.w = v3 - lse;
  *(float4*)(out + (size_t)v * FO + dg * 4) = o;
}

extern "C" void kernel_launch(void* const* d_in, const int* in_sizes, int n_in,
                              void* d_out, int out_size, void* d_ws, size_t ws_size,
                              hipStream_t stream) {
  const float* x  = (const float*)d_in[0];
  const int*   ei = (const int*)d_in[1];
  const float* W1 = (const float*)d_in[2];
  const float* b1 = (const float*)d_in[3];
  const float* W2 = (const float*)d_in[4];
  const float* b2 = (const float*)d_in[5];
  const int N = in_sizes[0] / FIN;
  const int E = in_sizes[1] / 2;
  float* out = (float*)d_out;

  size_t NP = ((size_t)N + 63) & ~(size_t)63;
  size_t EP = ((size_t)E + 63) & ~(size_t)63;
  int nb = (N + 255) / 256;
  int NB = (N + BNODES - 1) >> BSH;   // dst-buckets

  int*      deg     = (int*)d_ws;               // NP
  int*      rowoff  = deg + NP;                 // NP
  int*      bsum    = rowoff + NP;              // 512
  float*    dinv    = (float*)(bsum + 512);     // NP
  int*      histmat = (int*)(dinv + NP);        // NBMAX*NCHUNK
  int*      offmat  = histmat + (size_t)NBMAX * NCHUNK;  // NBMAX*NCHUNK
  int*      csr     = offmat + (size_t)NBMAX * NCHUNK;   // EP
  unsigned* part    = (unsigned*)(csr + EP);    // EP
  bf16_t*   w1t     = (bf16_t*)(part + EP);     // 64*512
  bf16_t*   w2t     = w1t + (size_t)FH * FIN;   // 32*64
  bf16_t*   P1      = w2t + (size_t)FO * FH;    // NP*64
  bf16_t*   h       = P1 + NP * FH;             // NP*64
  bf16_t*   P2      = h + NP * FH;              // NP*32

  int initN = (int)NP;
  if (initN < FIN * FH) initN = FIN * FH;
  k_init<<<(initN + 255) / 256, 256, 0, stream>>>(deg, (int)NP, W1, w1t, W2, w2t);
  k_histA<<<NCHUNK, 256, 0, stream>>>(ei + E, deg, histmat, E, NB);
  k_scan_block<<<nb, 256, 0, stream>>>(deg, rowoff, bsum, dinv, N);
  k_scan_bsum<<<1, 256, 0, stream>>>(bsum, nb);
  k_scan_add<<<nb, 256, 0, stream>>>(rowoff, bsum, N);
  k_scanB<<<NB, 256, 0, stream>>>(histmat, rowoff, offmat, NB);
  k_scatC<<<NCHUNK, 256, 0, stream>>>(ei, offmat, part, E, NB);
  k_csrb<<<NB, 256, 0, stream>>>(part, rowoff, csr, N, E);
  k_gemm1<<<(N + 63) / 64, 256, 0, stream>>>(x, w1t, dinv, P1, N);
  {
    int waves = (N + 3) / 4;
    k_gather1<<<(waves + 3) / 4, 256, 0, stream>>>(P1, csr, rowoff, deg, dinv, b1, h, N);
  }
  k_gemm2<<<(N + 63) / 64, 256, 0, stream>>>(h, w2t, dinv, P2, N);
  {
    int waves = (N + 7) / 8;
    k_g2final<<<(waves + 3) / 4, 256, 0, stream>>>(P2, csr, rowoff, deg, dinv, b2, out, N);
  }
}

// Round 9
// 259.141 us; speedup vs baseline: 4.3711x; 1.0199x over previous
//
#include <hip/hip_runtime.h>
#include <math.h>

#define FIN 512
#define FH  64
#define FO  32

#define BSH    9          // 512 nodes per dst-bucket
#define BNODES 512
#define NCHUNK 256        // radix chunk-blocks
#define BCAP   16384      // LDS csr capacity per bucket (mean 8192)
#define NBMAX  512

typedef __bf16 bf16_t;
typedef bf16_t bf16x8 __attribute__((ext_vector_type(8)));
typedef float  f32x4  __attribute__((ext_vector_type(4)));

__device__ __forceinline__ float bf_lo(unsigned u) {
  return __builtin_bit_cast(float, u << 16);
}
__device__ __forceinline__ float bf_hi(unsigned u) {
  return __builtin_bit_cast(float, u & 0xffff0000u);
}

// fused init: zero deg, build W1T bf16 [64][512], W2T bf16 [32][64]
__global__ __launch_bounds__(256) void k_init(int* __restrict__ p, int n2,
                                              const float* __restrict__ W1,
                                              bf16_t* __restrict__ w1t,
                                              const float* __restrict__ W2,
                                              bf16_t* __restrict__ w2t) {
  int i = blockIdx.x * 256 + threadIdx.x;
  if (i < n2) p[i] = 0;
  if (i < FIN * FH) {
    int c = i >> 9, k = i & 511;
    w1t[i] = (bf16_t)W1[(size_t)k * FH + c];
  }
  if (i < FH * FO) {
    int c = i >> 6, k = i & 63;
    w2t[i] = (bf16_t)W2[(size_t)k * FO + c];
  }
}

// radix pass A: per-chunk bucket histogram (LDS) + global deg histogram
__global__ __launch_bounds__(256) void k_histA(const int* __restrict__ dst,
                                               int* __restrict__ deg,
                                               int* __restrict__ histmat,
                                               int E, int NB) {
  __shared__ int lh[NBMAX];
  int t = threadIdx.x;
  int g = blockIdx.x;
  for (int i = t; i < NB; i += 256) lh[i] = 0;
  __syncthreads();
  int C = (E + NCHUNK - 1) / NCHUNK;
  int e0 = g * C, e1 = min(E, e0 + C);
  for (int e = e0 + t; e < e1; e += 256) {
    int d = dst[e];
    atomicAdd(&deg[d], 1);
    atomicAdd(&lh[d >> BSH], 1);
  }
  __syncthreads();
  for (int b = t; b < NB; b += 256) histmat[(size_t)b * NCHUNK + g] = lh[b];
}

__global__ __launch_bounds__(256) void k_scan_block(const int* __restrict__ deg,
                                                    int* __restrict__ rowoff,
                                                    int* __restrict__ bsum,
                                                    float* __restrict__ dinv, int n) {
  __shared__ int s[256];
  int t = threadIdx.x;
  int i = blockIdx.x * 256 + t;
  int v = (i < n) ? deg[i] : 0;
  s[t] = v;
  __syncthreads();
  #pragma unroll
  for (int off = 1; off < 256; off <<= 1) {
    int tmp = (t >= off) ? s[t - off] : 0;
    __syncthreads();
    s[t] += tmp;
    __syncthreads();
  }
  if (i < n) {
    rowoff[i] = s[t] - v;
    dinv[i] = rsqrtf((float)(v + 1));
  }
  if (t == 255) bsum[blockIdx.x] = s[255];
}

__global__ __launch_bounds__(256) void k_scan_bsum(int* __restrict__ bsum, int nb) {
  __shared__ int s[256];
  int t = threadIdx.x;
  int carry = 0;
  for (int base = 0; base < nb; base += 256) {
    int idx = base + t;
    int v = (idx < nb) ? bsum[idx] : 0;
    s[t] = v;
    __syncthreads();
    #pragma unroll
    for (int off = 1; off < 256; off <<= 1) {
      int tmp = (t >= off) ? s[t - off] : 0;
      __syncthreads();
      s[t] += tmp;
      __syncthreads();
    }
    if (idx < nb) bsum[idx] = s[t] - v + carry;
    carry += s[255];
    __syncthreads();
  }
}

__global__ __launch_bounds__(256) void k_scan_add(int* __restrict__ rowoff,
                                                  const int* __restrict__ bsum, int n) {
  int i = blockIdx.x * 256 + threadIdx.x;
  if (i < n) rowoff[i] += bsum[blockIdx.x];
}

// radix pass B: per-bucket exclusive scan over chunks + bucket base
__global__ __launch_bounds__(256) void k_scanB(const int* __restrict__ histmat,
                                               const int* __restrict__ rowoff,
                                               int* __restrict__ offmat, int NB) {
  __shared__ int s[NCHUNK];
  int b = blockIdx.x;
  int t = threadIdx.x;
  int v = histmat[(size_t)b * NCHUNK + t];
  s[t] = v;
  __syncthreads();
  #pragma unroll
  for (int off = 1; off < NCHUNK; off <<= 1) {
    int tmp = (t >= off) ? s[t - off] : 0;
    __syncthreads();
    s[t] += tmp;
    __syncthreads();
  }
  offmat[(size_t)b * NCHUNK + t] = s[t] - v + rowoff[(size_t)b << BSH];
}

// radix pass C: scatter packed (dlocal<<23 | src) into bucket-grouped part[]
__global__ __launch_bounds__(256) void k_scatC(const int* __restrict__ ei,
                                               const int* __restrict__ offmat,
                                               unsigned* __restrict__ part,
                                               int E, int NB) {
  __shared__ int lcur[NBMAX];
  int t = threadIdx.x;
  int g = blockIdx.x;
  for (int b = t; b < NB; b += 256) lcur[b] = offmat[(size_t)b * NCHUNK + g];
  __syncthreads();
  int C = (E + NCHUNK - 1) / NCHUNK;
  int e0 = g * C, e1 = min(E, e0 + C);
  for (int e = e0 + t; e < e1; e += 256) {
    int s = ei[e];
    int d = ei[E + e];
    int b = d >> BSH;
    int pos = atomicAdd(&lcur[b], 1);
    part[pos] = (unsigned)s | ((unsigned)(d & (BNODES - 1)) << 23);
  }
}

// per-bucket CSR build in LDS, coalesced dump
__global__ __launch_bounds__(256) void k_csrb(const unsigned* __restrict__ part,
                                              const int* __restrict__ rowoff,
                                              int* __restrict__ csr, int n, int E) {
  __shared__ int lro[BNODES];
  __shared__ int lcur[BNODES];
  __shared__ int lcsr[BCAP];
  int b = blockIdx.x;
  int base = b << BSH;
  int t = threadIdx.x;
  int bo = rowoff[base];
  int endIdx = base + BNODES;
  int bend = (endIdx < n) ? rowoff[endIdx] : E;
  int cnt = bend - bo;
  for (int i = t; i < BNODES; i += 256) {
    int node = base + i;
    lro[i] = (node < n) ? (rowoff[node] - bo) : cnt;
    lcur[i] = 0;
  }
  __syncthreads();
  const unsigned* pp = part + bo;
  if (cnt <= BCAP) {
    for (int j = t; j < cnt; j += 256) {
      unsigned pk = pp[j];
      int dl = (int)(pk >> 23);
      int pos = atomicAdd(&lcur[dl], 1);
      lcsr[lro[dl] + pos] = (int)(pk & 0x7FFFFFu);
    }
    __syncthreads();
    for (int j = t; j < cnt; j += 256) csr[bo + j] = lcsr[j];
  } else {
    for (int j = t; j < cnt; j += 256) {
      unsigned pk = pp[j];
      int dl = (int)(pk >> 23);
      int pos = atomicAdd(&lcur[dl], 1);
      csr[bo + lro[dl] + pos] = (int)(pk & 0x7FFFFFu);
    }
  }
}

// GEMM1 via MFMA: P1[n][64] (bf16) = dinv[n] * (x[n] @ W1). x-read-BW bound.
__global__ __launch_bounds__(256) void k_gemm1(const float* __restrict__ x,
                                               const bf16_t* __restrict__ w1t,
                                               const float* __restrict__ dinv,
                                               bf16_t* __restrict__ P1, int n) {
  int t = threadIdx.x;
  int w = t >> 6, l = t & 63;
  int rowBase = blockIdx.x * 64 + w * 16;
  int fr = l & 15, fk = l >> 4;
  int ar = rowBase + fr; if (ar >= n) ar = n - 1;
  const float* xp = x + (size_t)ar * FIN + fk * 8;
  const bf16_t* wb = w1t + (size_t)fr * FIN + fk * 8;

  f32x4 acc0 = {0.f, 0.f, 0.f, 0.f};
  f32x4 acc1 = {0.f, 0.f, 0.f, 0.f};
  f32x4 acc2 = {0.f, 0.f, 0.f, 0.f};
  f32x4 acc3 = {0.f, 0.f, 0.f, 0.f};

  #pragma unroll 4
  for (int kt = 0; kt < FIN; kt += 32) {
    float4 a0 = *(const float4*)(xp + kt);
    float4 a1 = *(const float4*)(xp + kt + 4);
    bf16x8 av;
    av[0] = (bf16_t)a0.x; av[1] = (bf16_t)a0.y; av[2] = (bf16_t)a0.z; av[3] = (bf16_t)a0.w;
    av[4] = (bf16_t)a1.x; av[5] = (bf16_t)a1.y; av[6] = (bf16_t)a1.z; av[7] = (bf16_t)a1.w;
    bf16x8 b0 = *(const bf16x8*)(wb + kt);
    bf16x8 b1 = *(const bf16x8*)(wb + (size_t)16 * FIN + kt);
    bf16x8 b2 = *(const bf16x8*)(wb + (size_t)32 * FIN + kt);
    bf16x8 b3 = *(const bf16x8*)(wb + (size_t)48 * FIN + kt);
    acc0 = __builtin_amdgcn_mfma_f32_16x16x32_bf16(av, b0, acc0, 0, 0, 0);
    acc1 = __builtin_amdgcn_mfma_f32_16x16x32_bf16(av, b1, acc1, 0, 0, 0);
    acc2 = __builtin_amdgcn_mfma_f32_16x16x32_bf16(av, b2, acc2, 0, 0, 0);
    acc3 = __builtin_amdgcn_mfma_f32_16x16x32_bf16(av, b3, acc3, 0, 0, 0);
  }

  #pragma unroll
  for (int rg = 0; rg < 4; rg++) {
    int grow = rowBase + fk * 4 + rg;
    if (grow < n) {
      float dv = dinv[grow];
      bf16_t* prow = P1 + (size_t)grow * FH + fr;
      prow[0]  = (bf16_t)(dv * acc0[rg]);
      prow[16] = (bf16_t)(dv * acc1[rg]);
      prow[32] = (bf16_t)(dv * acc2[rg]);
      prow[48] = (bf16_t)(dv * acc3[rg]);
    }
  }
}

// gather1: wave = 8 subgroups x 8 lanes x uint4 (16B); one node per subgroup.
// 4-unrolled edge walk -> 32 row-reads in flight per wave.
__global__ __launch_bounds__(256) void k_gather1(const bf16_t* __restrict__ P1,
                                                 const int* __restrict__ csr,
                                                 const int* __restrict__ rowoff,
                                                 const int* __restrict__ deg,
                                                 const float* __restrict__ dinv,
                                                 const float* __restrict__ b1,
                                                 bf16_t* __restrict__ h, int n) {
  int l = threadIdx.x & 63;
  int sg = l >> 3, dg = l & 7;
  int wv = (blockIdx.x * 256 + threadIdx.x) >> 6;
  int v = wv * 8 + sg;
  if (v >= n) return;
  const uint4* P1v = (const uint4*)P1;
  int base = rowoff[v];
  int cnt = deg[v];
  uint4 sv = P1v[(size_t)v * 8 + dg];  // self loop
  float a0 = bf_lo(sv.x), a1 = bf_hi(sv.x), a2 = bf_lo(sv.y), a3 = bf_hi(sv.y);
  float a4 = bf_lo(sv.z), a5 = bf_hi(sv.z), a6 = bf_lo(sv.w), a7 = bf_hi(sv.w);
  float c0 = 0.f, c1 = 0.f, c2 = 0.f, c3 = 0.f, c4 = 0.f, c5 = 0.f, c6 = 0.f, c7 = 0.f;
  int cnt4 = cnt & ~3;
  int j = 0;
  for (; j < cnt4; j += 4) {
    int u0 = csr[base + j];
    int u1 = csr[base + j + 1];
    int u2 = csr[base + j + 2];
    int u3 = csr[base + j + 3];
    uint4 r0 = P1v[(size_t)u0 * 8 + dg];
    uint4 r1 = P1v[(size_t)u1 * 8 + dg];
    uint4 r2 = P1v[(size_t)u2 * 8 + dg];
    uint4 r3 = P1v[(size_t)u3 * 8 + dg];
    a0 += bf_lo(r0.x); a1 += bf_hi(r0.x); a2 += bf_lo(r0.y); a3 += bf_hi(r0.y);
    a4 += bf_lo(r0.z); a5 += bf_hi(r0.z); a6 += bf_lo(r0.w); a7 += bf_hi(r0.w);
    c0 += bf_lo(r1.x); c1 += bf_hi(r1.x); c2 += bf_lo(r1.y); c3 += bf_hi(r1.y);
    c4 += bf_lo(r1.z); c5 += bf_hi(r1.z); c6 += bf_lo(r1.w); c7 += bf_hi(r1.w);
    a0 += bf_lo(r2.x); a1 += bf_hi(r2.x); a2 += bf_lo(r2.y); a3 += bf_hi(r2.y);
    a4 += bf_lo(r2.z); a5 += bf_hi(r2.z); a6 += bf_lo(r2.w); a7 += bf_hi(r2.w);
    c0 += bf_lo(r3.x); c1 += bf_hi(r3.x); c2 += bf_lo(r3.y); c3 += bf_hi(r3.y);
    c4 += bf_lo(r3.z); c5 += bf_hi(r3.z); c6 += bf_lo(r3.w); c7 += bf_hi(r3.w);
  }
  for (; j < cnt; j++) {
    int u = csr[base + j];
    uint4 r = P1v[(size_t)u * 8 + dg];
    a0 += bf_lo(r.x); a1 += bf_hi(r.x); a2 += bf_lo(r.y); a3 += bf_hi(r.y);
    a4 += bf_lo(r.z); a5 += bf_hi(r.z); a6 += bf_lo(r.w); a7 += bf_hi(r.w);
  }
  a0 += c0; a1 += c1; a2 += c2; a3 += c3;
  a4 += c4; a5 += c5; a6 += c6; a7 += c7;
  float dv = dinv[v];
  float4 bb0 = ((const float4*)b1)[dg * 2];
  float4 bb1 = ((const float4*)b1)[dg * 2 + 1];
  bf16x8 hv;
  hv[0] = (bf16_t)fmaxf(dv * a0 + bb0.x, 0.f);
  hv[1] = (bf16_t)fmaxf(dv * a1 + bb0.y, 0.f);
  hv[2] = (bf16_t)fmaxf(dv * a2 + bb0.z, 0.f);
  hv[3] = (bf16_t)fmaxf(dv * a3 + bb0.w, 0.f);
  hv[4] = (bf16_t)fmaxf(dv * a4 + bb1.x, 0.f);
  hv[5] = (bf16_t)fmaxf(dv * a5 + bb1.y, 0.f);
  hv[6] = (bf16_t)fmaxf(dv * a6 + bb1.z, 0.f);
  hv[7] = (bf16_t)fmaxf(dv * a7 + bb1.w, 0.f);
  ((bf16x8*)h)[(size_t)v * 8 + dg] = hv;
}

// GEMM2 via MFMA: P2[n][32] (bf16) = dinv[n] * (h[n] @ W2)
__global__ __launch_bounds__(256) void k_gemm2(const bf16_t* __restrict__ h,
                                               const bf16_t* __restrict__ w2t,
                                               const float* __restrict__ dinv,
                                               bf16_t* __restrict__ P2, int n) {
  int t = threadIdx.x;
  int w = t >> 6, l = t & 63;
  int rowBase = blockIdx.x * 64 + w * 16;
  int fr = l & 15, fk = l >> 4;
  int ar = rowBase + fr; if (ar >= n) ar = n - 1;
  const bf16_t* hp = h + (size_t)ar * FH + fk * 8;
  const bf16_t* wb0 = w2t + (size_t)fr * FH + fk * 8;
  const bf16_t* wb1 = w2t + (size_t)(fr + 16) * FH + fk * 8;

  f32x4 acc0 = {0.f, 0.f, 0.f, 0.f};
  f32x4 acc1 = {0.f, 0.f, 0.f, 0.f};
  #pragma unroll
  for (int kt = 0; kt < FH; kt += 32) {
    bf16x8 af = *(const bf16x8*)(hp + kt);
    bf16x8 b0 = *(const bf16x8*)(wb0 + kt);
    bf16x8 b1 = *(const bf16x8*)(wb1 + kt);
    acc0 = __builtin_amdgcn_mfma_f32_16x16x32_bf16(af, b0, acc0, 0, 0, 0);
    acc1 = __builtin_amdgcn_mfma_f32_16x16x32_bf16(af, b1, acc1, 0, 0, 0);
  }
  #pragma unroll
  for (int rg = 0; rg < 4; rg++) {
    int grow = rowBase + fk * 4 + rg;
    if (grow < n) {
      float dv = dinv[grow];
      P2[(size_t)grow * FO + fr]      = (bf16_t)(dv * acc0[rg]);
      P2[(size_t)grow * FO + fr + 16] = (bf16_t)(dv * acc1[rg]);
    }
  }
}

// gather2 + bias + log_softmax: wave = 16 subgroups x 4 lanes x uint4; one node each.
// 4-unrolled -> 64 rows in flight per wave. Softmax reduces over 4 lanes (xor 1,2).
__global__ __launch_bounds__(256) void k_g2final(const bf16_t* __restrict__ P2,
                                                 const int* __restrict__ csr,
                                                 const int* __restrict__ rowoff,
                                                 const int* __restrict__ deg,
                                                 const float* __restrict__ dinv,
                                                 const float* __restrict__ b2,
                                                 float* __restrict__ out, int n) {
  int l = threadIdx.x & 63;
  int sg = l >> 2, dg = l & 3;
  int wv = (blockIdx.x * 256 + threadIdx.x) >> 6;
  int v = wv * 16 + sg;
  if (v >= n) return;
  const uint4* P2v = (const uint4*)P2;
  int base = rowoff[v];
  int cnt = deg[v];
  uint4 sv = P2v[(size_t)v * 4 + dg];  // self loop
  float a0 = bf_lo(sv.x), a1 = bf_hi(sv.x), a2 = bf_lo(sv.y), a3 = bf_hi(sv.y);
  float a4 = bf_lo(sv.z), a5 = bf_hi(sv.z), a6 = bf_lo(sv.w), a7 = bf_hi(sv.w);
  float c0 = 0.f, c1 = 0.f, c2 = 0.f, c3 = 0.f, c4 = 0.f, c5 = 0.f, c6 = 0.f, c7 = 0.f;
  int cnt4 = cnt & ~3;
  int j = 0;
  for (; j < cnt4; j += 4) {
    int u0 = csr[base + j];
    int u1 = csr[base + j + 1];
    int u2 = csr[base + j + 2];
    int u3 = csr[base + j + 3];
    uint4 r0 = P2v[(size_t)u0 * 4 + dg];
    uint4 r1 = P2v[(size_t)u1 * 4 + dg];
    uint4 r2 = P2v[(size_t)u2 * 4 + dg];
    uint4 r3 = P2v[(size_t)u3 * 4 + dg];
    a0 += bf_lo(r0.x); a1 += bf_hi(r0.x); a2 += bf_lo(r0.y); a3 += bf_hi(r0.y);
    a4 += bf_lo(r0.z); a5 += bf_hi(r0.z); a6 += bf_lo(r0.w); a7 += bf_hi(r0.w);
    c0 += bf_lo(r1.x); c1 += bf_hi(r1.x); c2 += bf_lo(r1.y); c3 += bf_hi(r1.y);
    c4 += bf_lo(r1.z); c5 += bf_hi(r1.z); c6 += bf_lo(r1.w); c7 += bf_hi(r1.w);
    a0 += bf_lo(r2.x); a1 += bf_hi(r2.x); a2 += bf_lo(r2.y); a3 += bf_hi(r2.y);
    a4 += bf_lo(r2.z); a5 += bf_hi(r2.z); a6 += bf_lo(r2.w); a7 += bf_hi(r2.w);
    c0 += bf_lo(r3.x); c1 += bf_hi(r3.x); c2 += bf_lo(r3.y); c3 += bf_hi(r3.y);
    c4 += bf_lo(r3.z); c5 += bf_hi(r3.z); c6 += bf_lo(r3.w); c7 += bf_hi(r3.w);
  }
  for (; j < cnt; j++) {
    int u = csr[base + j];
    uint4 r = P2v[(size_t)u * 4 + dg];
    a0 += bf_lo(r.x); a1 += bf_hi(r.x); a2 += bf_lo(r.y); a3 += bf_hi(r.y);
    a4 += bf_lo(r.z); a5 += bf_hi(r.z); a6 += bf_lo(r.w); a7 += bf_hi(r.w);
  }
  a0 += c0; a1 += c1; a2 += c2; a3 += c3;
  a4 += c4; a5 += c5; a6 += c6; a7 += c7;
  float dv = dinv[v];
  float4 bb0 = ((const float4*)b2)[dg * 2];
  float4 bb1 = ((const float4*)b2)[dg * 2 + 1];
  float val[8];
  val[0] = dv * a0 + bb0.x; val[1] = dv * a1 + bb0.y;
  val[2] = dv * a2 + bb0.z; val[3] = dv * a3 + bb0.w;
  val[4] = dv * a4 + bb1.x; val[5] = dv * a5 + bb1.y;
  val[6] = dv * a6 + bb1.z; val[7] = dv * a7 + bb1.w;
  float m = val[0];
  #pragma unroll
  for (int q = 1; q < 8; q++) m = fmaxf(m, val[q]);
  m = fmaxf(m, __shfl_xor(m, 1, 64));
  m = fmaxf(m, __shfl_xor(m, 2, 64));
  float se = 0.f;
  #pragma unroll
  for (int q = 0; q < 8; q++) se += expf(val[q] - m);
  se += __shfl_xor(se, 1, 64);
  se += __shfl_xor(se, 2, 64);
  float lse = m + logf(se);
  float4 o0, o1;
  o0.x = val[0] - lse; o0.y = val[1] - lse; o0.z = val[2] - lse; o0.w = val[3] - lse;
  o1.x = val[4] - lse; o1.y = val[5] - lse; o1.z = val[6] - lse; o1.w = val[7] - lse;
  float* orow = out + (size_t)v * FO + dg * 8;
  *(float4*)orow = o0;
  *(float4*)(orow + 4) = o1;
}

extern "C" void kernel_launch(void* const* d_in, const int* in_sizes, int n_in,
                              void* d_out, int out_size, void* d_ws, size_t ws_size,
                              hipStream_t stream) {
  const float* x  = (const float*)d_in[0];
  const int*   ei = (const int*)d_in[1];
  const float* W1 = (const float*)d_in[2];
  const float* b1 = (const float*)d_in[3];
  const float* W2 = (const float*)d_in[4];
  const float* b2 = (const float*)d_in[5];
  const int N = in_sizes[0] / FIN;
  const int E = in_sizes[1] / 2;
  float* out = (float*)d_out;

  size_t NP = ((size_t)N + 63) & ~(size_t)63;
  size_t EP = ((size_t)E + 63) & ~(size_t)63;
  int nb = (N + 255) / 256;
  int NB = (N + BNODES - 1) >> BSH;

  int*      deg     = (int*)d_ws;               // NP
  int*      rowoff  = deg + NP;                 // NP
  int*      bsum    = rowoff + NP;              // 512
  float*    dinv    = (float*)(bsum + 512);     // NP
  int*      histmat = (int*)(dinv + NP);        // NBMAX*NCHUNK
  int*      offmat  = histmat + (size_t)NBMAX * NCHUNK;  // NBMAX*NCHUNK
  int*      csr     = offmat + (size_t)NBMAX * NCHUNK;   // EP
  unsigned* part    = (unsigned*)(csr + EP);    // EP
  bf16_t*   w1t     = (bf16_t*)(part + EP);     // 64*512
  bf16_t*   w2t     = w1t + (size_t)FH * FIN;   // 32*64
  bf16_t*   P1      = w2t + (size_t)FO * FH;    // NP*64
  bf16_t*   h       = P1 + NP * FH;             // NP*64
  bf16_t*   P2      = h + NP * FH;              // NP*32

  int initN = (int)NP;
  if (initN < FIN * FH) initN = FIN * FH;
  k_init<<<(initN + 255) / 256, 256, 0, stream>>>(deg, (int)NP, W1, w1t, W2, w2t);
  k_histA<<<NCHUNK, 256, 0, stream>>>(ei + E, deg, histmat, E, NB);
  k_scan_block<<<nb, 256, 0, stream>>>(deg, rowoff, bsum, dinv, N);
  k_scan_bsum<<<1, 256, 0, stream>>>(bsum, nb);
  k_scan_add<<<nb, 256, 0, stream>>>(rowoff, bsum, N);
  k_scanB<<<NB, 256, 0, stream>>>(histmat, rowoff, offmat, NB);
  k_scatC<<<NCHUNK, 256, 0, stream>>>(ei, offmat, part, E, NB);
  k_csrb<<<NB, 256, 0, stream>>>(part, rowoff, csr, N, E);
  k_gemm1<<<(N + 63) / 64, 256, 0, stream>>>(x, w1t, dinv, P1, N);
  {
    int waves = (N + 7) / 8;
    k_gather1<<<(waves + 3) / 4, 256, 0, stream>>>(P1, csr, rowoff, deg, dinv, b1, h, N);
  }
  k_gemm2<<<(N + 63) / 64, 256, 0, stream>>>(h, w2t, dinv, P2, N);
  {
    int waves = (N + 15) / 16;
    k_g2final<<<(waves + 3) / 4, 256, 0, stream>>>(P2, csr, rowoff, deg, dinv, b2, out, N);
  }
}